// Round 1
// baseline (4128.418 us; speedup 1.0000x reference)
//
#include <hip/hip_runtime.h>
#include <math.h>

#define VV 32000
#define DD 512
#define NLAYER 6
#define BB 2
#define SS 2048
#define HH 8
#define NST 16
#define KC 4
#define DI 1024
#define TOT 2312            // DI + DI + H + H*N + H*N = 2312
#define BS (BB*SS)          // 4096
#define CHUNK 32
#define NCHUNK (SS/CHUNK)   // 64

// ---------------------------------------------------------------- embed
__global__ void embed_kernel(const int* __restrict__ tokens,
                             const float* __restrict__ embed,
                             float* __restrict__ x) {
    int row = blockIdx.x;                 // 0..BS-1
    int tok = tokens[row];
    const float4* src = (const float4*)(embed + (size_t)tok * DD);
    float4* dst = (float4*)(x + (size_t)row * DD);
    dst[threadIdx.x] = src[threadIdx.x];  // 128 threads * float4 = 512 floats
}

// ---------------------------------------------------------------- rmsnorm
__global__ void rmsnorm_kernel(const float* __restrict__ x,
                               const float* __restrict__ w,
                               float* __restrict__ xn) {
    int row = blockIdx.x;
    int tid = threadIdx.x;  // 256
    const float* xr = x + (size_t)row * DD;
    float a = xr[tid], b = xr[tid + 256];
    float v = a * a + b * b;
    for (int off = 32; off > 0; off >>= 1) v += __shfl_down(v, off, 64);
    __shared__ float wsum[4];
    if ((tid & 63) == 0) wsum[tid >> 6] = v;
    __syncthreads();
    float tot = wsum[0] + wsum[1] + wsum[2] + wsum[3];
    float sc = rsqrtf(tot * (1.0f / DD) + 1e-6f);
    float* xo = xn + (size_t)row * DD;
    xo[tid]       = a * sc * w[tid];
    xo[tid + 256] = b * sc * w[tid + 256];
}

// ---------------------------------------------------------------- GEMM (NT): C[M,N] = A[M,K] * Bw[N,K]^T (+src) (+bias)
template <int ADD_SRC, int ADD_BIAS>
__global__ __launch_bounds__(256) void gemm_nt(const float* __restrict__ A,
                                               const float* __restrict__ Bw,
                                               const float* __restrict__ src,
                                               const float* __restrict__ bias,
                                               float* __restrict__ C,
                                               int M, int N, int Kd) {
    __shared__ float As[16][68];   // [k][m], padded to keep 16B alignment, low conflicts
    __shared__ float Bs[16][68];   // [k][n]
    int tid = threadIdx.x;
    int m0 = blockIdx.y * 64;
    int n0 = blockIdx.x * 64;
    int tx = tid & 15, ty = tid >> 4;
    float acc[4][4] = {};
    int lr = tid >> 2;   // 0..63: tile row loaded by this thread
    int lq = tid & 3;    // float4 quad within 16-wide k slice

    for (int k0 = 0; k0 < Kd; k0 += 16) {
        {
            int gm = m0 + lr;
            float4 av = make_float4(0.f, 0.f, 0.f, 0.f);
            if (gm < M) av = *(const float4*)(A + (size_t)gm * Kd + k0 + lq * 4);
            As[lq * 4 + 0][lr] = av.x; As[lq * 4 + 1][lr] = av.y;
            As[lq * 4 + 2][lr] = av.z; As[lq * 4 + 3][lr] = av.w;
            int gn = n0 + lr;
            float4 bv = make_float4(0.f, 0.f, 0.f, 0.f);
            if (gn < N) bv = *(const float4*)(Bw + (size_t)gn * Kd + k0 + lq * 4);
            Bs[lq * 4 + 0][lr] = bv.x; Bs[lq * 4 + 1][lr] = bv.y;
            Bs[lq * 4 + 2][lr] = bv.z; Bs[lq * 4 + 3][lr] = bv.w;
        }
        __syncthreads();
        #pragma unroll
        for (int kk = 0; kk < 16; ++kk) {
            float4 a4 = *(const float4*)&As[kk][ty * 4];
            float4 b4 = *(const float4*)&Bs[kk][tx * 4];
            float av[4] = {a4.x, a4.y, a4.z, a4.w};
            float bv[4] = {b4.x, b4.y, b4.z, b4.w};
            #pragma unroll
            for (int i = 0; i < 4; ++i)
                #pragma unroll
                for (int j = 0; j < 4; ++j)
                    acc[i][j] = fmaf(av[i], bv[j], acc[i][j]);
        }
        __syncthreads();
    }

    #pragma unroll
    for (int i = 0; i < 4; ++i) {
        int gm = m0 + ty * 4 + i;
        if (gm >= M) break;
        int gnb = n0 + tx * 4;
        if (gnb + 3 < N) {
            float4 r = make_float4(acc[i][0], acc[i][1], acc[i][2], acc[i][3]);
            if (ADD_SRC) {
                float4 sv = *(const float4*)(src + (size_t)gm * N + gnb);
                r.x += sv.x; r.y += sv.y; r.z += sv.z; r.w += sv.w;
            }
            if (ADD_BIAS) {
                float4 bv2 = *(const float4*)(bias + gnb);
                r.x += bv2.x; r.y += bv2.y; r.z += bv2.z; r.w += bv2.w;
            }
            *(float4*)(C + (size_t)gm * N + gnb) = r;
        } else {
            for (int j = 0; j < 4; ++j) {
                int gn = gnb + j;
                if (gn < N) {
                    float r = acc[i][j];
                    if (ADD_SRC) r += src[(size_t)gm * N + gn];
                    if (ADD_BIAS) r += bias[gn];
                    C[(size_t)gm * N + gn] = r;
                }
            }
        }
    }
}

// ------------------------------------------------- conv + silu + head-mean + dt/dA
// Note: post-silu xi is ONLY consumed via the per-head mean -> we never store it.
__global__ void conv_state_kernel(const float* __restrict__ p,
                                  const float* __restrict__ cw,
                                  const float* __restrict__ dtb,
                                  const float* __restrict__ alog,
                                  float* __restrict__ x_in,
                                  float* __restrict__ dtv,
                                  float* __restrict__ dAv) {
    int bs = blockIdx.x;        // b*SS + s
    int s = bs & (SS - 1);
    int tid = threadIdx.x;      // 256
    const float* prow = p + (size_t)bs * TOT + DI;  // xi slice of p
    float hacc = 0.f;
    #pragma unroll
    for (int j = 0; j < 4; ++j) {
        int c = tid * 4 + j;    // all 4 channels in the same head (head = c/128)
        const float* w = cw + c * KC;
        float v = w[3] * prow[c];
        if (s >= 1) v += w[2] * prow[c - TOT];
        if (s >= 2) v += w[1] * prow[c - 2 * TOT];
        if (s >= 3) v += w[0] * prow[c - 3 * TOT];
        float sv = v / (1.f + expf(-v));   // silu
        hacc += sv;
    }
    for (int off = 16; off > 0; off >>= 1) hacc += __shfl_down(hacc, off, 32);
    __shared__ float hs[HH];
    if ((tid & 31) == 0) hs[tid >> 5] = hacc;
    __syncthreads();
    if (tid < HH) {
        x_in[(size_t)bs * HH + tid] = hs[tid] * (1.f / 128.f);
        float raw = p[(size_t)bs * TOT + 2 * DI + tid] + dtb[tid];
        float dt = (raw > 20.f) ? raw : log1pf(expf(raw));  // softplus
        float A = -expf(alog[tid]);
        dtv[(size_t)bs * HH + tid] = dt;
        dAv[(size_t)bs * HH + tid] = expf(dt * A);
    }
}

// ---------------------------------------------------------------- chunked scan
// Phase A: per-chunk local scan from 0 + carry product
__global__ void scan_phaseA(const float* __restrict__ p,
                            const float* __restrict__ x_in,
                            const float* __restrict__ dtv,
                            const float* __restrict__ dAv,
                            float* __restrict__ carryP,
                            float* __restrict__ hend) {
    int wid = blockIdx.x;                  // BB*HH*(NCHUNK/4) blocks of 64
    int cg = wid & (NCHUNK / 4 - 1);       // 0..15
    int bh = wid / (NCHUNK / 4);           // 0..15
    int b = bh >> 3, h = bh & 7;
    int lane = threadIdx.x;
    int csub = lane >> 4, n = lane & 15;
    int chunk = cg * 4 + csub;
    int s0 = chunk * CHUNK;
    float hn = 0.f, P = 1.f;
    const float* pB = p + 2 * DI + HH + h * NST + n;
    for (int t = 0; t < CHUNK; ++t) {
        int idx = b * SS + s0 + t;
        float da = dAv[(size_t)idx * HH + h];
        float u = dtv[(size_t)idx * HH + h] * x_in[(size_t)idx * HH + h] * pB[(size_t)idx * TOT];
        hn = fmaf(da, hn, u);
        P *= da;
    }
    hend[((size_t)bh * NCHUNK + chunk) * NST + n] = hn;
    if (n == 0) carryP[(size_t)bh * NCHUNK + chunk] = P;
}

// Phase B: sequential scan over the 64 chunk carries (one tiny block)
__global__ void scan_phaseB(const float* __restrict__ carryP,
                            const float* __restrict__ hend,
                            float* __restrict__ hstart) {
    int t = threadIdx.x;   // 256 = BB*HH*NST
    int bh = t >> 4, n = t & 15;
    float hc = 0.f;
    for (int c = 0; c < NCHUNK; ++c) {
        size_t base = (size_t)bh * NCHUNK + c;
        hstart[base * NST + n] = hc;
        hc = carryP[base] * hc + hend[base * NST + n];
    }
}

// Phase C: replay with correct h_start, emit y = sum_n h*C
__global__ void scan_phaseC(const float* __restrict__ p,
                            const float* __restrict__ x_in,
                            const float* __restrict__ dtv,
                            const float* __restrict__ dAv,
                            const float* __restrict__ hstart,
                            float* __restrict__ y) {
    int wid = blockIdx.x;
    int cg = wid & (NCHUNK / 4 - 1);
    int bh = wid / (NCHUNK / 4);
    int b = bh >> 3, h = bh & 7;
    int lane = threadIdx.x;
    int csub = lane >> 4, n = lane & 15;
    int chunk = cg * 4 + csub;
    int s0 = chunk * CHUNK;
    float hn = hstart[((size_t)bh * NCHUNK + chunk) * NST + n];
    const float* pB = p + 2 * DI + HH + h * NST + n;
    const float* pC = pB + HH * NST;
    for (int t = 0; t < CHUNK; ++t) {
        int idx = b * SS + s0 + t;
        float da = dAv[(size_t)idx * HH + h];
        float u = dtv[(size_t)idx * HH + h] * x_in[(size_t)idx * HH + h] * pB[(size_t)idx * TOT];
        hn = fmaf(da, hn, u);
        float contrib = hn * pC[(size_t)idx * TOT];
        for (int off = 8; off > 0; off >>= 1) contrib += __shfl_down(contrib, off, 16);
        if (n == 0) y[(size_t)idx * HH + h] = contrib;
    }
}

// ---------------------------------------------------------------- y-proj + silu(z) gate
__global__ void gate_kernel(const float* __restrict__ p,
                            const float* __restrict__ y,
                            const float* __restrict__ yw,
                            float* __restrict__ g) {
    int bs = blockIdx.x;
    int tid = threadIdx.x;  // 256
    __shared__ float ys[HH];
    if (tid < HH) ys[tid] = y[(size_t)bs * HH + tid];
    __syncthreads();
    const float* prow = p + (size_t)bs * TOT;   // z slice at offset 0
    #pragma unroll
    for (int j = 0; j < 4; ++j) {
        int i = tid * 4 + j;
        const float* w = yw + i * HH;
        float yd = 0.f;
        #pragma unroll
        for (int h = 0; h < HH; ++h) yd = fmaf(ys[h], w[h], yd);
        float z = prow[i];
        float sz = z / (1.f + expf(-z));
        g[(size_t)bs * DI + i] = yd * sz;
    }
}

// ---------------------------------------------------------------- final layernorm
__global__ void layernorm_kernel(const float* __restrict__ x,
                                 const float* __restrict__ w,
                                 const float* __restrict__ bbias,
                                 float* __restrict__ out) {
    int row = blockIdx.x;
    int tid = threadIdx.x;  // 256
    const float* xr = x + (size_t)row * DD;
    float a = xr[tid], c = xr[tid + 256];
    float sum = a + c;
    for (int off = 32; off > 0; off >>= 1) sum += __shfl_down(sum, off, 64);
    __shared__ float w1[4];
    __shared__ float w2[4];
    if ((tid & 63) == 0) w1[tid >> 6] = sum;
    __syncthreads();
    float mu = (w1[0] + w1[1] + w1[2] + w1[3]) * (1.0f / DD);
    float da = a - mu, dc = c - mu;
    float v = da * da + dc * dc;
    for (int off = 32; off > 0; off >>= 1) v += __shfl_down(v, off, 64);
    if ((tid & 63) == 0) w2[tid >> 6] = v;
    __syncthreads();
    float var = (w2[0] + w2[1] + w2[2] + w2[3]) * (1.0f / DD);
    float sc = rsqrtf(var + 1e-5f);
    out[(size_t)row * DD + tid]       = da * sc * w[tid] + bbias[tid];
    out[(size_t)row * DD + tid + 256] = dc * sc * w[tid + 256] + bbias[tid + 256];
}

// ---------------------------------------------------------------- launch
extern "C" void kernel_launch(void* const* d_in, const int* in_sizes, int n_in,
                              void* d_out, int out_size, void* d_ws, size_t ws_size,
                              hipStream_t stream) {
    const int*   tokens   = (const int*)d_in[0];
    const float* embed    = (const float*)d_in[1];
    const float* rms_w    = (const float*)d_in[2];
    const float* in_proj  = (const float*)d_in[3];
    const float* conv_w   = (const float*)d_in[4];
    const float* dt_bias  = (const float*)d_in[5];
    const float* A_log    = (const float*)d_in[6];
    const float* y_proj   = (const float*)d_in[7];
    const float* out_proj = (const float*)d_in[8];
    const float* ln_w     = (const float*)d_in[9];
    const float* ln_b     = (const float*)d_in[10];
    const float* head_w   = (const float*)d_in[11];
    const float* head_b   = (const float*)d_in[12];
    float* out = (float*)d_out;

    float* ws = (float*)d_ws;
    size_t off = 0;
    float* x      = ws + off; off += (size_t)BS * DD;
    float* xn     = ws + off; off += (size_t)BS * DD;
    float* p      = ws + off; off += (size_t)BS * TOT;
    float* x_in   = ws + off; off += (size_t)BS * HH;
    float* dtv    = ws + off; off += (size_t)BS * HH;
    float* dAv    = ws + off; off += (size_t)BS * HH;
    float* y      = ws + off; off += (size_t)BS * HH;
    float* g      = ws + off; off += (size_t)BS * DI;
    float* carryP = ws + off; off += (size_t)BB * HH * NCHUNK;
    float* hend   = ws + off; off += (size_t)BB * HH * NCHUNK * NST;
    float* hstart = ws + off; off += (size_t)BB * HH * NCHUNK * NST;
    // total ~72 MB of f32 workspace

    embed_kernel<<<BS, 128, 0, stream>>>(tokens, embed, x);

    for (int l = 0; l < NLAYER; ++l) {
        rmsnorm_kernel<<<BS, 256, 0, stream>>>(x, rms_w + l * DD, xn);

        dim3 g1((TOT + 63) / 64, BS / 64);
        gemm_nt<0, 0><<<g1, 256, 0, stream>>>(xn, in_proj + (size_t)l * TOT * DD,
                                              nullptr, nullptr, p, BS, TOT, DD);

        conv_state_kernel<<<BS, 256, 0, stream>>>(p, conv_w + l * DI * KC,
                                                  dt_bias + l * HH, A_log + l * HH,
                                                  x_in, dtv, dAv);

        scan_phaseA<<<BB * HH * (NCHUNK / 4), 64, 0, stream>>>(p, x_in, dtv, dAv, carryP, hend);
        scan_phaseB<<<1, 256, 0, stream>>>(carryP, hend, hstart);
        scan_phaseC<<<BB * HH * (NCHUNK / 4), 64, 0, stream>>>(p, x_in, dtv, dAv, hstart, y);

        gate_kernel<<<BS, 256, 0, stream>>>(p, y, y_proj + (size_t)l * DI * HH, g);

        dim3 g2(DD / 64, BS / 64);
        gemm_nt<1, 0><<<g2, 256, 0, stream>>>(g, out_proj + (size_t)l * DD * DI,
                                              x, nullptr, x, BS, DD, DI);
    }

    layernorm_kernel<<<BS, 256, 0, stream>>>(x, ln_w, ln_b, xn);

    dim3 g3(VV / 64, BS / 64);
    gemm_nt<0, 1><<<g3, 256, 0, stream>>>(xn, head_w, nullptr, head_b, out, BS, VV, DD);
}